// Round 9
// baseline (7126.871 us; speedup 1.0000x reference)
//
#include <hip/hip_runtime.h>
#include <hip/hip_bf16.h>
#include <cstdint>
#include <cstddef>

#define BB 64
#define TT 512
#define DD 256
#define HH 512
#define G4 2048   // 4*H

typedef __bf16 bf16x8 __attribute__((ext_vector_type(8)));
typedef __bf16 bf16x4 __attribute__((ext_vector_type(4)));
typedef float  f32x4  __attribute__((ext_vector_type(4)));
typedef unsigned long long ull_t;

// bits[15:14] of every bf16 h element are the step tag:
//   01 / 10 = alternating step tags (1 + ((step>>1)&1))
//   11 = init sentinel (memset 0xFF)
//   (valid h in (0,1) has bits[15:14] == 00 before tagging)
#define TAGM 0xC000C000C000C000ULL

// Safety: bounded spin; on overflow the thread proceeds (test fails visibly
// instead of hanging the container).
#define SPIN_CAP (1 << 16)

// A-slab row stride in bf16 elements: 768 K + 8 pad => 1552B rows.
// Row stride 1552B = 388 dwords, 388 % 32 = 4 banks => fragment reads are
// 2-way bank aliased (free, m136) instead of 16-way at stride 1536.
#define AS 776

__device__ __forceinline__ float sigf(float x) {
  return 1.0f / (1.0f + __expf(-x));
}

// Agent-coherent load: reads the coherence point (MALL). ~600 GB/s aggregate
// (measured across rounds 1-7) -- the scarce resource this design economizes.
__device__ __forceinline__ ull_t coh_load_u64(const __bf16* p) {
  return __hip_atomic_load(reinterpret_cast<const ull_t*>(p),
                           __ATOMIC_RELAXED, __HIP_MEMORY_SCOPE_AGENT);
}
// Agent-scope atomic swap publish: executes AT the coherence point.
__device__ __forceinline__ void coh_pub_u32(unsigned* p, unsigned v) {
  (void)__hip_atomic_exchange(p, v, __ATOMIC_RELAXED, __HIP_MEMORY_SCOPE_AGENT);
}

// Convert x fp32 [B][T][D] -> bf16 (same layout) in ws.
__global__ void cvt_x_kernel(const float* __restrict__ x, __bf16* __restrict__ xb) {
  int i = (blockIdx.x * 256 + threadIdx.x) * 4;
  float4 v = *(const float4*)(x + i);
  bf16x4 o;
  o[0] = (__bf16)v.x; o[1] = (__bf16)v.y; o[2] = (__bf16)v.z; o[3] = (__bf16)v.w;
  *(bf16x4*)(xb + i) = o;
}

// Persistent bidirectional LSTM: SHARED-GATHER + gate-packed waves.
// Grid: 64 blocks x 1024 threads (16 waves). Block (dir=bx>>5, rg=(bx>>3)&3,
// ug=bx&7) owns batch rows [16rg,16rg+16) x hidden units [64ug,64ug+64).
// Rounds 1-7 measured the agent-coherent read path at ~600 GB/s aggregate and
// showed per-step time == gather_traffic / 600GB/s regardless of sync scheme.
// This design cuts traffic 4x: ONE cooperative 16KB h gather per block per
// step (per-thread tag spin, de-tag, stage into a double-buffered LDS A-slab),
// consumed by 16 gate-packed waves (4 units x 4 gates in MFMA N=16 -> only 24
// resident B-frags = 96 VGPR, the size proven not to spill in R6).
// Publish: R4's proven tag-in-data 4B agent atomics. One barrier per step
// (double-buffered slab makes it sufficient).
__launch_bounds__(1024, 1)
__global__ void lstm_kernel(const __bf16* __restrict__ xb,
                            const float* __restrict__ Wf, const float* __restrict__ Uf,
                            const float* __restrict__ bf_,
                            const float* __restrict__ Wb, const float* __restrict__ Ub,
                            const float* __restrict__ bb_,
                            __bf16* __restrict__ hbuf,          // [2 dir][2 phase][64][512]
                            float* __restrict__ out,            // d_out
                            __bf16* __restrict__ hsb) {         // [T][B][H] bwd halves
  const int bx  = blockIdx.x;
  const int dir = bx >> 5;
  const int rg  = (bx >> 3) & 3;       // row group: batch rows [16rg, 16rg+16)
  const int ug  = bx & 7;              // unit group: units [64ug, 64ug+64)
  const float* Wd = dir ? Wb : Wf;
  const float* Ud = dir ? Ub : Uf;
  const float* bd = dir ? bb_ : bf_;
  __bf16* hb = hbuf + (size_t)dir * 2 * BB * HH;

  const int tid  = threadIdx.x;
  const int wv   = tid >> 6;           // wave id 0..15 -> 4-unit column tile
  const int lane = tid & 63;
  const int j    = lane & 15;          // A local row / packed B col
  const int q    = lane >> 4;          // quad
  const int gt   = j >> 2;             // gate (Keras order i,f,g,o)
  const int u    = j & 3;              // unit within wave's 4
  const int colg = ug * 64 + wv * 4 + u;  // global hidden unit

  // A-slab: [2 buf][16 rows][AS bf16]; k 0..255 = x, 256..767 = h (de-tagged)
  __shared__ __bf16 aslab[2][16][AS];

  // staging roles
  const int hrow_s = tid >> 6;         // h stage: row 0..15, 16B chunk (tid&63)
  const int hcol_s = (tid & 63) * 8;
  const int xrow_s = (tid >> 5) & 15;  // x stage (tid<512): row, 16B chunk
  const int xcol_s = (tid & 31) * 8;

  // ---- one-time: gather this wave's 24 packed B-fragments (96 VGPR, resident)
  bf16x8 wfrag[24];
#pragma unroll
  for (int kt = 0; kt < 24; ++kt) {
    const int col = gt * HH + colg;
    bf16x8 v;
#pragma unroll
    for (int e = 0; e < 8; ++e) {
      const int k = kt * 32 + q * 8 + e;
      const float w = (k < DD) ? Wd[(size_t)k * G4 + col]
                               : Ud[(size_t)(k - DD) * G4 + col];
      v[e] = (__bf16)w;
    }
    wfrag[kt] = v;
  }
  const float bg = bd[gt * HH + colg];

  float cst[4] = {0.f, 0.f, 0.f, 0.f};   // cell state for (local rows q*4+r, unit u)
  const size_t outTail = (size_t)BB * TT * HH;

  for (int tau = 0; tau < TT; ++tau) {
    const int t = dir ? (TT - 1 - tau) : tau;
    const int buf = tau & 1;

    // ---- stage x rows for time t (threads < 512; 8KB) ----
    if (tid < 512) {
      bf16x8 xv = *(const bf16x8*)(xb + ((size_t)(rg * 16 + xrow_s) * TT + t) * DD + xcol_s);
      *(bf16x8*)&aslab[buf][xrow_s][xcol_s] = xv;
    }

    // ---- stage h_tau (all 1024 threads; 16KB; per-thread tag spin) ----
    if (tau) {
      const __bf16* hp = hb + (size_t)buf * (BB * HH)
                            + (size_t)(rg * 16 + hrow_s) * HH + hcol_s;
      const ull_t epat = (ull_t)(1u + ((unsigned)(tau >> 1) & 1u)) * 0x4000400040004000ULL;
      ull_t a = coh_load_u64(hp);
      ull_t b = coh_load_u64(hp + 4);
      int guard = 0;
      while (((a & TAGM) != epat) | ((b & TAGM) != epat)) {
        if (++guard > SPIN_CAP) break;   // fail visibly, never hang
        __builtin_amdgcn_s_sleep(1);
        a = coh_load_u64(hp);
        b = coh_load_u64(hp + 4);
      }
      union { ull_t uq[2]; bf16x8 v; } uu;
      uu.uq[0] = a & ~TAGM;
      uu.uq[1] = b & ~TAGM;
      *(bf16x8*)&aslab[buf][hrow_s][256 + hcol_s] = uu.v;
    }

    __syncthreads();   // slab[buf] complete; double-buffer => one barrier/step

    // ---- compute: 8 x-MFMAs (+16 h-MFMAs when tau>0) off the slab ----
    f32x4 acc = (f32x4){bg, bg, bg, bg};
    const __bf16* arow = &aslab[buf][j][q * 8];
#pragma unroll
    for (int kt = 0; kt < 8; ++kt) {
      bf16x8 a = *(const bf16x8*)(arow + kt * 32);
      acc = __builtin_amdgcn_mfma_f32_16x16x32_bf16(a, wfrag[kt], acc, 0, 0, 0);
    }
    if (tau) {
#pragma unroll
      for (int kt = 8; kt < 24; ++kt) {
        bf16x8 a = *(const bf16x8*)(arow + kt * 32);
        acc = __builtin_amdgcn_mfma_f32_16x16x32_bf16(a, wfrag[kt], acc, 0, 0, 0);
      }
    }

    // ---- gate exchange among sister lanes (j, j^4, j^8, j^12) [R6, verified]
    f32x4 vb, vc, vd;
#pragma unroll
    for (int e = 0; e < 4; ++e) {
      vb[e] = __shfl_xor(acc[e], 4);
      vc[e] = __shfl_xor(acc[e], 8);
      vd[e] = __shfl_xor(vb[e], 8);
    }
    const bool p  = (gt & 1) != 0;
    const bool h2 = (gt & 2) != 0;

    const unsigned ptag = ((1u + ((unsigned)((tau + 1) >> 1) & 1u)) << 14);
    __bf16* hnext = hb + (size_t)((tau + 1) & 1) * (BB * HH);
    unsigned myv[4];
#pragma unroll
    for (int r = 0; r < 4; ++r) {
      const float i1 = p ? vb[r] : acc[r];
      const float i2 = p ? vd[r] : vc[r];
      const float iA = p ? acc[r] : vb[r];
      const float iB = p ? vc[r] : vd[r];
      const float zi = h2 ? i2 : i1;         // gate i
      const float zf = h2 ? iB : iA;         // gate f
      const float zg = h2 ? i1 : i2;         // gate g
      const float zo = h2 ? iA : iB;         // gate o
      const float gi = sigf(zi), gf = sigf(zf), gg = sigf(zg), go = sigf(zo);
      const float cn = gf * cst[r] + gi * gg;
      cst[r] = cn;
      const float hn = go * sigf(cn);
      union { __bf16 b; unsigned short us; } cv;
      cv.b = (__bf16)hn;                     // hn in (0,1) => bits[15:14] == 00
      myv[r] = (unsigned)cv.us | ptag;
      if (gt == 0) {                         // one lane per (row, unit) stores
        const int orow = rg * 16 + q * 4 + r;
        if (dir == 0) {
          out[(size_t)orow * (TT * HH) + (size_t)t * HH + colg] = 0.5f * hn;
        } else {
          hsb[(size_t)t * (BB * HH) + (size_t)orow * HH + colg] = (__bf16)hn;
        }
        if (tau == TT - 1) {
          float* base = out + outTail + (size_t)dir * (2 * BB * HH);
          base[(size_t)orow * HH + colg] = hn;                 // hF / hB
          base[(size_t)BB * HH + (size_t)orow * HH + colg] = cn; // cF / cB
        }
      }
    }

    // publish h_{tau+1}: pair adjacent units, (gt==0, u even) lanes, 4B atomics
    unsigned pr[4];
#pragma unroll
    for (int r = 0; r < 4; ++r) pr[r] = __shfl_xor((int)myv[r], 1);
    if (gt == 0 && (u & 1) == 0) {
#pragma unroll
      for (int r = 0; r < 4; ++r) {
        const int orow = rg * 16 + q * 4 + r;
        unsigned pk = (myv[r] & 0xFFFFu) | (pr[r] << 16);
        coh_pub_u32((unsigned*)&hnext[(size_t)orow * HH + colg], pk);
      }
    }
  }
}

// out[b,t,c] += 0.5 * hsb[t,b,c]
__global__ void combine_kernel(float* __restrict__ out, const __bf16* __restrict__ hsb) {
  const size_t i = ((size_t)blockIdx.x * 256 + threadIdx.x) * 4;
  const size_t b = i >> 18;
  const size_t t = (i >> 9) & 511;
  const size_t c = i & 511;
  bf16x4 hv = *(const bf16x4*)(hsb + t * (BB * HH) + b * HH + c);
  float4 v = *(float4*)(out + i);
  v.x += 0.5f * (float)hv[0];
  v.y += 0.5f * (float)hv[1];
  v.z += 0.5f * (float)hv[2];
  v.w += 0.5f * (float)hv[3];
  *(float4*)(out + i) = v;
}

extern "C" void kernel_launch(void* const* d_in, const int* in_sizes, int n_in,
                              void* d_out, int out_size, void* d_ws, size_t ws_size,
                              hipStream_t stream) {
  (void)in_sizes; (void)n_in; (void)out_size; (void)ws_size;
  const float* x   = (const float*)d_in[0];
  // d_in[1] = 'hidden' is unused by the reference (h0 = c0 = 0)
  const float* Wf  = (const float*)d_in[2];
  const float* Uf  = (const float*)d_in[3];
  const float* bf_ = (const float*)d_in[4];
  const float* Wb  = (const float*)d_in[5];
  const float* Ub  = (const float*)d_in[6];
  const float* bb_ = (const float*)d_in[7];
  float* out = (float*)d_out;
  char* ws = (char*)d_ws;

  // ws layout:
  //   [1024, 263168)  : hbuf  2 dir x 2 phase x 64 x 512 bf16 (0xFF = sentinel)
  //   [512K, 16.5M)   : x bf16 [B][T][D]
  //   [16.5M, 48.5M)  : hsb bf16 [T][B][H]
  __bf16* hbuf = (__bf16*)(ws + 1024);
  __bf16* xb   = (__bf16*)(ws + (1 << 19));
  __bf16* hsb  = (__bf16*)(ws + (1 << 19) + (size_t)BB * TT * DD * 2);

  hipMemsetAsync(ws, 0xFF, 1 << 19, stream);  // tag 11 = "never written" sentinel
  cvt_x_kernel<<<dim3((BB * TT * DD) / 1024), dim3(256), 0, stream>>>(x, xb);
  lstm_kernel<<<dim3(64), dim3(1024), 0, stream>>>(xb, Wf, Uf, bf_, Wb, Ub, bb_,
                                                   hbuf, out, hsb);
  combine_kernel<<<dim3((BB * TT * HH) / 1024), dim3(256), 0, stream>>>(out, hsb);
}